// Round 9
// baseline (371.215 us; speedup 1.0000x reference)
//
#include <hip/hip_runtime.h>
#include <hip/hip_bf16.h>
#include <hip/hip_cooperative_groups.h>

namespace cg = cooperative_groups;

#define DD 128
#define LN_EPS 1e-5f
#define BCAP 3072      // per-bin record cap (avg 2048, +22 sigma)
#define MAXBIN 1024    // LDS histogram capacity (NBIN = 782 for N=100000)
#define CHUNK 4096     // edges per binning block

typedef __bf16 bf16x8 __attribute__((ext_vector_type(8)));
typedef float f32x4 __attribute__((ext_vector_type(4)));

__device__ __forceinline__ float bflo(unsigned int u) { return __uint_as_float(u << 16); }
__device__ __forceinline__ float bfhi(unsigned int u) { return __uint_as_float(u & 0xffff0000u); }

__device__ __forceinline__ void gload_lds16(const void* g, void* lds) {
    __builtin_amdgcn_global_load_lds(
        (const __attribute__((address_space(1))) unsigned int*)g,
        (__attribute__((address_space(3))) unsigned int*)lds, 16, 0, 0);
}

// ---- fused preprocessing (cooperative): hist -> scanbin -> scan -> place -> sort/CSR
// plus feat/weight bf16 packing folded into phase A. One launch replaces 7.
__global__ __launch_bounds__(256) void k_prep(const float* __restrict__ feat,
                                              const float* __restrict__ W,
                                              const float* __restrict__ Wf,
                                              const int* __restrict__ src,
                                              const int* __restrict__ dst,
                                              unsigned short* __restrict__ fb,
                                              unsigned short* __restrict__ wcat,
                                              int* __restrict__ H, int* __restrict__ C,
                                              int* __restrict__ binoff,
                                              unsigned int* __restrict__ rec,
                                              unsigned int* __restrict__ sortedg,
                                              int* __restrict__ nodestart,
                                              int* __restrict__ nodedeg,
                                              int N, int E, int E4, int NBLK, int NBIN,
                                              int n8) {
    cg::grid_group grid = cg::this_grid();
    __shared__ int shm[3584];  // 14.3 KB, reused across phases
    const int b = blockIdx.x, tid = threadIdx.x;
    const int gtid = b * 256 + tid, gsz = gridDim.x * 256;

    // ---- A1: per-block LDS histogram of this block's edge chunk ----
    for (int j = tid; j < NBIN; j += 256) shm[j] = 0;
    __syncthreads();
    {
        int base = b * CHUNK;
        int end = base + CHUNK < E4 ? base + CHUNK : E4;
        for (int i = base + tid; i < end; i += 256) atomicAdd(&shm[dst[i] >> 7], 1);
    }
    __syncthreads();
    for (int j = tid; j < NBIN; j += 256) H[(size_t)j * NBLK + b] = shm[j];

    // ---- A2: pack feat fp32 -> bf16 (grid-stride) ----
    for (int i = gtid; i < n8; i += gsz) {
        const float4* p = (const float4*)feat + (size_t)i * 2;
        float4 v0 = p[0], v1 = p[1];
        float vv[8] = {v0.x, v0.y, v0.z, v0.w, v1.x, v1.y, v1.z, v1.w};
        unsigned short u[8];
#pragma unroll
        for (int j = 0; j < 8; j++) {
            __hip_bfloat16 bb = __float2bfloat16(vv[j]);
            u[j] = *reinterpret_cast<unsigned short*>(&bb);
        }
        uint4 o;
        o.x = u[0] | ((unsigned)u[1] << 16);
        o.y = u[2] | ((unsigned)u[3] << 16);
        o.z = u[4] | ((unsigned)u[5] << 16);
        o.w = u[6] | ((unsigned)u[7] << 16);
        ((uint4*)fb)[i] = o;
    }

    // ---- A3: pack weights -> col-major concat [t][col 0..383][k] ----
    for (int i = gtid; i < 4 * 384 * 128; i += gsz) {
        int t = i / (384 * 128);
        int r = i % (384 * 128);
        int c = r / 128, k = r % 128;
        float v = (c < 128) ? W[((size_t)t * 128 + k) * 128 + c]
                            : Wf[((size_t)t * 128 + k) * 256 + (c - 128)];
        __hip_bfloat16 bb = __float2bfloat16(v);
        wcat[i] = *reinterpret_cast<unsigned short*>(&bb);
    }

    grid.sync();

    // ---- B: per-bin exclusive scan across blocks (one wave per bin) ----
    {
        int wv = gtid >> 6;
        int lane = tid & 63;
        if (wv < NBIN) {
            int* row = H + (size_t)wv * NBLK;
            int run = 0;
            for (int base = 0; base < NBLK; base += 64) {
                int idx = base + lane;
                int v = (idx < NBLK) ? row[idx] : 0;
                int s = v;
#pragma unroll
                for (int o = 1; o < 64; o <<= 1) {
                    int u = __shfl_up(s, o, 64);
                    if (lane >= o) s += u;
                }
                if (idx < NBLK) row[idx] = run + s - v;  // exclusive
                run += __shfl(s, 63, 64);
            }
            if (lane == 0) C[wv] = run;
        }
    }

    grid.sync();

    // ---- C: exclusive scan over NBIN bin totals (block 0 only, 4 bins/thread) ----
    if (b == 0) {
        int v[4];
        int tot = 0;
#pragma unroll
        for (int j = 0; j < 4; j++) {
            int idx = tid * 4 + j;
            v[j] = (idx < NBIN) ? C[idx] : 0;
            tot += v[j];
        }
        shm[tid] = tot;
        __syncthreads();
        for (int st = 1; st < 256; st <<= 1) {
            int t = shm[tid];
            int add = (tid >= st) ? shm[tid - st] : 0;
            __syncthreads();
            shm[tid] = t + add;
            __syncthreads();
        }
        int run = shm[tid] - tot;  // exclusive
#pragma unroll
        for (int j = 0; j < 4; j++) {
            int idx = tid * 4 + j;
            if (idx < NBIN) binoff[idx] = run;
            run += v[j];
        }
        if (tid == 255) binoff[NBIN] = shm[255];
    }

    grid.sync();

    // ---- D: place records at deterministic offsets (LDS atomics only) ----
    for (int j = tid; j < NBIN; j += 256) shm[j] = binoff[j] + H[(size_t)j * NBLK + b];
    __syncthreads();
    {
        int base = b * CHUNK;
        int end = base + CHUNK < E4 ? base + CHUNK : E4;
        for (int i = base + tid; i < end; i += 256) {
            int d = dst[i];
            int t = i / E;
            unsigned int r = ((unsigned)(d & 127) << 19) | (unsigned)(t * N + src[i]);
            int pos = atomicAdd(&shm[d >> 7], 1);
            rec[pos] = r;
        }
    }

    grid.sync();

    // ---- E: per-bin LDS counting sort -> global CSR (bins grid-strided) ----
    int* lcnt = shm;
    int* soff = shm + 128;
    int* sfill = shm + 256;
    int* tmp = shm + 384;
    unsigned int* sorted = (unsigned int*)(shm + 512);
    for (int bin = b; bin < NBIN; bin += gridDim.x) {
        __syncthreads();  // protect shm reuse across iterations
        const int s0 = binoff[bin];
        int n = binoff[bin + 1] - s0;
        if (n > BCAP) n = BCAP;

        if (tid < 128) lcnt[tid] = 0;
        __syncthreads();
        for (int j = tid; j < n; j += 256) atomicAdd(&lcnt[rec[s0 + j] >> 19], 1);
        __syncthreads();
        if (tid < 128) tmp[tid] = lcnt[tid];
        __syncthreads();
        for (int st = 1; st < 128; st <<= 1) {
            int t = 0, a = 0;
            if (tid < 128) {
                t = tmp[tid];
                a = (tid >= st) ? tmp[tid - st] : 0;
            }
            __syncthreads();
            if (tid < 128) tmp[tid] = t + a;
            __syncthreads();
        }
        if (tid < 128) {
            int ex = tmp[tid] - lcnt[tid];
            soff[tid] = ex;
            sfill[tid] = ex;
        }
        __syncthreads();
        for (int j = tid; j < n; j += 256) {
            unsigned int r = rec[s0 + j];
            int p = atomicAdd(&sfill[r >> 19], 1);
            sorted[p] = r & 0x7FFFFu;
        }
        __syncthreads();
        for (int j = tid; j < n; j += 256) sortedg[s0 + j] = sorted[j];
        if (tid < 128) {
            int node = bin * 128 + tid;
            if (node < N) {
                nodestart[node] = s0 + soff[tid];
                nodedeg[node] = lcnt[tid];
            }
        }
    }
}

// ---- fused GEMM + FiLM, B-stationary: m_t = relu(gamma*msg + beta) ----
__global__ __launch_bounds__(256, 2) void k_gemm_film(const unsigned short* __restrict__ featb,
                                                      const unsigned short* __restrict__ wcat,
                                                      unsigned short* __restrict__ m, int N,
                                                      int NT) {
    __shared__ unsigned char smem[2 * 16384];  // double-buffered 64x128 bf16, XOR-swizzled
    const int t = blockIdx.y;
    const int tid = threadIdx.x;
    const int w = tid >> 6, lane = tid & 63;
    const int lr = lane & 15, kg = lane >> 4;
    const int cbase = w * 32;

    const unsigned short* wt = wcat + (size_t)t * 384 * 128;
    bf16x8 B[4][3][2];
#pragma unroll
    for (int kkI = 0; kkI < 4; kkI++)
#pragma unroll
        for (int mat = 0; mat < 3; mat++)
#pragma unroll
            for (int cj = 0; cj < 2; cj++) {
                int col = mat * 128 + cbase + cj * 16 + lr;
                B[kkI][mat][cj] = *(const bf16x8*)(wt + (size_t)col * 128 + kkI * 32 + kg * 8);
            }

    auto stage = [&](int buf, int r0) {
#pragma unroll
        for (int it = 0; it < 4; it++) {
            int row = it * 16 + w * 4 + (lane >> 4);
            int gr = r0 + row;
            if (gr >= N) gr = N - 1;
            int x = ((lane & 15) * 16) ^ ((row & 7) << 4);
            const unsigned char* g = (const unsigned char*)featb + (size_t)gr * 256 + x;
            gload_lds16(g, smem + buf * 16384 + it * 4096 + w * 1024);
        }
    };

    unsigned short* mt = m + (size_t)t * N * DD;
    int buf = 0;
    int tile = blockIdx.x;
    if (tile < NT) stage(0, tile * 64);

    for (; tile < NT; tile += gridDim.x) {
        __syncthreads();
        int nxt = tile + gridDim.x;
        if (nxt < NT) stage(buf ^ 1, nxt * 64);

        const unsigned char* sm = smem + buf * 16384;
        f32x4 acc[4][3][2] = {};
#pragma unroll
        for (int kkI = 0; kkI < 4; kkI++) {
            bf16x8 a[4];
#pragma unroll
            for (int mi = 0; mi < 4; mi++) {
                int row = mi * 16 + lr;
                int kb = kkI * 64 + kg * 16;
                a[mi] = *(const bf16x8*)(sm + row * 256 + (kb ^ ((row & 7) << 4)));
            }
#pragma unroll
            for (int mi = 0; mi < 4; mi++)
#pragma unroll
                for (int mat = 0; mat < 3; mat++)
#pragma unroll
                    for (int cj = 0; cj < 2; cj++)
                        acc[mi][mat][cj] = __builtin_amdgcn_mfma_f32_16x16x32_bf16(
                            a[mi], B[kkI][mat][cj], acc[mi][mat][cj], 0, 0, 0);
        }

        const int r0 = tile * 64;
#pragma unroll
        for (int mi = 0; mi < 4; mi++)
#pragma unroll
            for (int cj = 0; cj < 2; cj++)
#pragma unroll
                for (int r = 0; r < 4; r++) {
                    int row = r0 + mi * 16 + kg * 4 + r;
                    if (row < N) {
                        float v = acc[mi][1][cj][r] * acc[mi][0][cj][r] + acc[mi][2][cj][r];
                        v = fmaxf(v, 0.0f);
                        __hip_bfloat16 bb = __float2bfloat16(v);
                        mt[(size_t)row * DD + cbase + cj * 16 + lr] =
                            *reinterpret_cast<unsigned short*>(&bb);
                    }
                }
        buf ^= 1;
    }
}

// ---- CSR gather + fused LayerNorm (at combined L3+HBM delivery roofline) ----
__global__ __launch_bounds__(256) void k_agg_ln(const unsigned int* __restrict__ sortedg,
                                                const int* __restrict__ nodestart,
                                                const int* __restrict__ nodedeg,
                                                const char* __restrict__ mbase,
                                                const float* __restrict__ lnw,
                                                const float* __restrict__ lnb,
                                                float* __restrict__ out, int N) {
    const int wv = threadIdx.x >> 6, lane = threadIdx.x & 63;
    const int node = blockIdx.x * 4 + wv;
    if (node >= N) return;
    const int start = nodestart[node], deg = nodedeg[node];
    const int q = lane >> 4, sl = lane & 15;
    const unsigned soff = (unsigned)sl * 16u;

    float a[8] = {0.f, 0.f, 0.f, 0.f, 0.f, 0.f, 0.f, 0.f};

    int e = 0;
    for (; e + 16 <= deg; e += 16) {
        unsigned r0 = sortedg[start + e + q];
        unsigned r1 = sortedg[start + e + 4 + q];
        unsigned r2 = sortedg[start + e + 8 + q];
        unsigned r3 = sortedg[start + e + 12 + q];
        uint4 p0 = *(const uint4*)(mbase + (r0 * 256u + soff));
        uint4 p1 = *(const uint4*)(mbase + (r1 * 256u + soff));
        uint4 p2 = *(const uint4*)(mbase + (r2 * 256u + soff));
        uint4 p3 = *(const uint4*)(mbase + (r3 * 256u + soff));
        a[0] += bflo(p0.x) + bflo(p1.x) + bflo(p2.x) + bflo(p3.x);
        a[1] += bfhi(p0.x) + bfhi(p1.x) + bfhi(p2.x) + bfhi(p3.x);
        a[2] += bflo(p0.y) + bflo(p1.y) + bflo(p2.y) + bflo(p3.y);
        a[3] += bfhi(p0.y) + bfhi(p1.y) + bfhi(p2.y) + bfhi(p3.y);
        a[4] += bflo(p0.z) + bflo(p1.z) + bflo(p2.z) + bflo(p3.z);
        a[5] += bfhi(p0.z) + bfhi(p1.z) + bfhi(p2.z) + bfhi(p3.z);
        a[6] += bflo(p0.w) + bflo(p1.w) + bflo(p2.w) + bflo(p3.w);
        a[7] += bfhi(p0.w) + bfhi(p1.w) + bfhi(p2.w) + bfhi(p3.w);
    }
    for (; e + 4 <= deg; e += 4) {
        unsigned r0 = sortedg[start + e + q];
        uint4 p0 = *(const uint4*)(mbase + (r0 * 256u + soff));
        a[0] += bflo(p0.x);
        a[1] += bfhi(p0.x);
        a[2] += bflo(p0.y);
        a[3] += bfhi(p0.y);
        a[4] += bflo(p0.z);
        a[5] += bfhi(p0.z);
        a[6] += bflo(p0.w);
        a[7] += bfhi(p0.w);
    }
    if (e < deg) {
        int idx = e + q;
        float w = (idx < deg) ? 1.0f : 0.0f;
        if (idx >= deg) idx = deg - 1;  // clamp to a valid edge (weight 0)
        unsigned r0 = sortedg[start + idx];
        uint4 p0 = *(const uint4*)(mbase + (r0 * 256u + soff));
        a[0] += w * bflo(p0.x);
        a[1] += w * bfhi(p0.x);
        a[2] += w * bflo(p0.y);
        a[3] += w * bfhi(p0.y);
        a[4] += w * bflo(p0.z);
        a[5] += w * bfhi(p0.z);
        a[6] += w * bflo(p0.w);
        a[7] += w * bfhi(p0.w);
    }

#pragma unroll
    for (int j = 0; j < 8; j++) {
        a[j] += __shfl_xor(a[j], 16, 64);
        a[j] += __shfl_xor(a[j], 32, 64);
    }
    float s = 0.f, ss = 0.f;
#pragma unroll
    for (int j = 0; j < 8; j++) {
        s += a[j];
        ss += a[j] * a[j];
    }
#pragma unroll
    for (int o = 1; o < 16; o <<= 1) {
        s += __shfl_xor(s, o, 64);
        ss += __shfl_xor(ss, o, 64);
    }
    float mu = s * (1.0f / 128.0f);
    float var = ss * (1.0f / 128.0f) - mu * mu;
    float rstd = rsqrtf(var + LN_EPS);
    if (q == 0) {
        float4 w0 = ((const float4*)lnw)[sl * 2];
        float4 w1 = ((const float4*)lnw)[sl * 2 + 1];
        float4 b0 = ((const float4*)lnb)[sl * 2];
        float4 b1 = ((const float4*)lnb)[sl * 2 + 1];
        float4 o0, o1;
        o0.x = (a[0] - mu) * rstd * w0.x + b0.x;
        o0.y = (a[1] - mu) * rstd * w0.y + b0.y;
        o0.z = (a[2] - mu) * rstd * w0.z + b0.z;
        o0.w = (a[3] - mu) * rstd * w0.w + b0.w;
        o1.x = (a[4] - mu) * rstd * w1.x + b1.x;
        o1.y = (a[5] - mu) * rstd * w1.y + b1.y;
        o1.z = (a[6] - mu) * rstd * w1.z + b1.z;
        o1.w = (a[7] - mu) * rstd * w1.w + b1.w;
        ((float4*)(out + (size_t)node * DD))[sl * 2] = o0;
        ((float4*)(out + (size_t)node * DD))[sl * 2 + 1] = o1;
    }
}

extern "C" void kernel_launch(void* const* d_in, const int* in_sizes, int n_in,
                              void* d_out, int out_size, void* d_ws, size_t ws_size,
                              hipStream_t stream) {
    const float* feat = (const float*)d_in[0];
    const float* W    = (const float*)d_in[1];
    const float* Wf   = (const float*)d_in[2];
    const float* lnw  = (const float*)d_in[3];
    const float* lnb  = (const float*)d_in[4];
    const int* src    = (const int*)d_in[5];
    const int* dst    = (const int*)d_in[6];
    float* out = (float*)d_out;

    int N = in_sizes[0] / DD;   // 100000
    int E = in_sizes[5] / 4;    // 400000
    int E4 = 4 * E;
    int NB = (N + 127) >> 7;    // 782 bins
    int NBLK = (E4 + CHUNK - 1) / CHUNK;  // 391
    int NT = (N + 63) / 64;     // 1563 row tiles
    int n8 = N * DD / 8;

    size_t off = 0;
    char* ws = (char*)d_ws;
    auto alloc = [&](size_t bytes) -> void* {
        void* p = ws + off;
        off += (bytes + 255) & ~(size_t)255;
        return p;
    };
    unsigned short* m     = (unsigned short*)alloc((size_t)4 * N * DD * 2);  // 102.4 MB
    unsigned short* featb = (unsigned short*)alloc((size_t)N * DD * 2);      // 25.6 MB
    unsigned short* wcat  = (unsigned short*)alloc((size_t)4 * 384 * 128 * 2);
    int* H      = (int*)alloc((size_t)NB * NBLK * 4);                        // 1.2 MB
    int* C      = (int*)alloc((size_t)NB * 4);
    int* binoff = (int*)alloc((size_t)(NB + 1) * 4);
    unsigned int* rec     = (unsigned int*)alloc((size_t)E4 * 4);            // 6.4 MB
    unsigned int* sortedg = (unsigned int*)alloc((size_t)E4 * 4);            // 6.4 MB
    int* nodestart = (int*)alloc((size_t)N * 4);
    int* nodedeg   = (int*)alloc((size_t)N * 4);
    if (off > ws_size) return;

    {
        void* args[] = {(void*)&feat, (void*)&W, (void*)&Wf, (void*)&src, (void*)&dst,
                        (void*)&featb, (void*)&wcat, (void*)&H, (void*)&C, (void*)&binoff,
                        (void*)&rec, (void*)&sortedg, (void*)&nodestart, (void*)&nodedeg,
                        (void*)&N, (void*)&E, (void*)&E4, (void*)&NBLK, (void*)&NB,
                        (void*)&n8};
        hipLaunchCooperativeKernel((void*)k_prep, dim3(NBLK), dim3(256), args, 0, stream);
    }
    dim3 gg(128, 4);
    k_gemm_film<<<gg, 256, 0, stream>>>(featb, wcat, m, N, NT);
    k_agg_ln<<<(N + 3) / 4, 256, 0, stream>>>(sortedg, nodestart, nodedeg,
                                              (const char*)m, lnw, lnb, out, N);
}

// Round 10
// 177.961 us; speedup vs baseline: 2.0859x; 2.0859x over previous
//
#include <hip/hip_runtime.h>
#include <hip/hip_bf16.h>

#define DD 128
#define LN_EPS 1e-5f
#define BCAP 3072      // per-bin record cap (avg 2048, +22 sigma)
#define MAXBIN 1024    // LDS histogram capacity (NBIN = 782 for N=100000)
#define CHUNK 4096     // edges per binning block

typedef __bf16 bf16x8 __attribute__((ext_vector_type(8)));
typedef float f32x4 __attribute__((ext_vector_type(4)));

__device__ __forceinline__ float bflo(unsigned int u) { return __uint_as_float(u << 16); }
__device__ __forceinline__ float bfhi(unsigned int u) { return __uint_as_float(u & 0xffff0000u); }

__device__ __forceinline__ void gload_lds16(const void* g, void* lds) {
    __builtin_amdgcn_global_load_lds(
        (const __attribute__((address_space(1))) unsigned int*)g,
        (__attribute__((address_space(3))) unsigned int*)lds, 16, 0, 0);
}

// ---- fused head: per-chunk histogram (blocks < NBLK) + feat/weight bf16 packing
// (all blocks, grid-stride). All three are independent streaming passes.
__global__ __launch_bounds__(256) void k_head(const float* __restrict__ feat,
                                              const float* __restrict__ W,
                                              const float* __restrict__ Wf,
                                              const int* __restrict__ dst,
                                              unsigned short* __restrict__ fb,
                                              unsigned short* __restrict__ wcat,
                                              int* __restrict__ H,
                                              int E4, int NBLK, int NBIN, int n8) {
    __shared__ int h[MAXBIN];
    const int b = blockIdx.x, tid = threadIdx.x;

    if (b < NBLK) {
        for (int j = tid; j < NBIN; j += 256) h[j] = 0;
        __syncthreads();
        int base = b * CHUNK;
        int end = base + CHUNK < E4 ? base + CHUNK : E4;
        for (int i = base + tid; i < end; i += 256) atomicAdd(&h[dst[i] >> 7], 1);
        __syncthreads();
        for (int j = tid; j < NBIN; j += 256) H[(size_t)j * NBLK + b] = h[j];
    }

    const int gtid = b * 256 + tid, gsz = gridDim.x * 256;

    // pack feat fp32 -> bf16 (8 elems per iter)
    for (int i = gtid; i < n8; i += gsz) {
        const float4* p = (const float4*)feat + (size_t)i * 2;
        float4 v0 = p[0], v1 = p[1];
        float vv[8] = {v0.x, v0.y, v0.z, v0.w, v1.x, v1.y, v1.z, v1.w};
        unsigned short u[8];
#pragma unroll
        for (int j = 0; j < 8; j++) {
            __hip_bfloat16 bb = __float2bfloat16(vv[j]);
            u[j] = *reinterpret_cast<unsigned short*>(&bb);
        }
        uint4 o;
        o.x = u[0] | ((unsigned)u[1] << 16);
        o.y = u[2] | ((unsigned)u[3] << 16);
        o.z = u[4] | ((unsigned)u[5] << 16);
        o.w = u[6] | ((unsigned)u[7] << 16);
        ((uint4*)fb)[i] = o;
    }

    // pack weights -> col-major concat [t][col 0..383][k]
    for (int i = gtid; i < 4 * 384 * 128; i += gsz) {
        int t = i / (384 * 128);
        int r = i % (384 * 128);
        int c = r / 128, k = r % 128;
        float v = (c < 128) ? W[((size_t)t * 128 + k) * 128 + c]
                            : Wf[((size_t)t * 128 + k) * 256 + (c - 128)];
        __hip_bfloat16 bb = __float2bfloat16(v);
        wcat[i] = *reinterpret_cast<unsigned short*>(&bb);
    }
}

// ---- P2: per-bin exclusive scan across blocks (one wave per bin), in place ----
__global__ __launch_bounds__(256) void k_scanbin(int* __restrict__ H, int* __restrict__ C,
                                                 int NBLK, int NBIN) {
    const int wv = (blockIdx.x * 256 + threadIdx.x) >> 6;
    const int lane = threadIdx.x & 63;
    if (wv >= NBIN) return;
    int* row = H + (size_t)wv * NBLK;
    int run = 0;
    for (int base = 0; base < NBLK; base += 64) {
        int idx = base + lane;
        int v = (idx < NBLK) ? row[idx] : 0;
        int s = v;
#pragma unroll
        for (int o = 1; o < 64; o <<= 1) {
            int u = __shfl_up(s, o, 64);
            if (lane >= o) s += u;
        }
        if (idx < NBLK) row[idx] = run + s - v;   // exclusive
        run += __shfl(s, 63, 64);
    }
    if (lane == 0) C[wv] = run;
}

// ---- P3: exclusive scan over NBIN bin totals (one block) ----
__global__ __launch_bounds__(1024) void k_scan(const int* __restrict__ cnt,
                                               int* __restrict__ off, int NB) {
    __shared__ int s[1024];
    int tid = threadIdx.x;
    s[tid] = (tid < NB) ? cnt[tid] : 0;
    __syncthreads();
    for (int st = 1; st < 1024; st <<= 1) {
        int t = s[tid];
        int a = (tid >= st) ? s[tid - st] : 0;
        __syncthreads();
        s[tid] = t + a;
        __syncthreads();
    }
    if (tid < NB) {
        off[tid] = s[tid] - cnt[tid];
        if (tid == NB - 1) off[NB] = s[tid];
    }
}

// ---- P4: place records at deterministic offsets; LDS atomics only ----
__global__ __launch_bounds__(256) void k_place2(const int* __restrict__ src,
                                                const int* __restrict__ dst,
                                                const int* __restrict__ H,
                                                const int* __restrict__ binoff,
                                                unsigned int* __restrict__ rec,
                                                int N, int E, int E4, int NBLK, int NBIN) {
    __shared__ int fill[MAXBIN];
    const int b = blockIdx.x;
    for (int j = threadIdx.x; j < NBIN; j += 256)
        fill[j] = binoff[j] + H[(size_t)j * NBLK + b];
    __syncthreads();
    int base = b * CHUNK;
    int end = base + CHUNK < E4 ? base + CHUNK : E4;
    for (int i = base + threadIdx.x; i < end; i += 256) {
        int d = dst[i];
        int t = i / E;
        unsigned int r = ((unsigned)(d & 127) << 19) | (unsigned)(t * N + src[i]);
        int pos = atomicAdd(&fill[d >> 7], 1);
        rec[pos] = r;
    }
}

// ---- P5: per-bin LDS counting sort -> global CSR (sorted edges + start/deg) ----
__global__ __launch_bounds__(256) void k_sortout(const unsigned int* __restrict__ rec,
                                                 const int* __restrict__ binoff,
                                                 unsigned int* __restrict__ sortedg,
                                                 int* __restrict__ nodestart,
                                                 int* __restrict__ nodedeg, int N) {
    __shared__ int lcnt[128], soff[128], sfill[128], tmp[128];
    __shared__ unsigned int sorted[BCAP];
    const int b = blockIdx.x, tid = threadIdx.x;
    const int s0 = binoff[b];
    int n = binoff[b + 1] - s0;
    if (n > BCAP) n = BCAP;

    if (tid < 128) lcnt[tid] = 0;
    __syncthreads();
    for (int j = tid; j < n; j += 256) atomicAdd(&lcnt[rec[s0 + j] >> 19], 1);
    __syncthreads();
    if (tid < 128) tmp[tid] = lcnt[tid];
    __syncthreads();
    for (int st = 1; st < 128; st <<= 1) {
        int t = 0, a = 0;
        if (tid < 128) {
            t = tmp[tid];
            a = (tid >= st) ? tmp[tid - st] : 0;
        }
        __syncthreads();
        if (tid < 128) tmp[tid] = t + a;
        __syncthreads();
    }
    if (tid < 128) {
        int ex = tmp[tid] - lcnt[tid];
        soff[tid] = ex;
        sfill[tid] = ex;
    }
    __syncthreads();
    for (int j = tid; j < n; j += 256) {
        unsigned int r = rec[s0 + j];
        int p = atomicAdd(&sfill[r >> 19], 1);
        sorted[p] = r & 0x7FFFFu;
    }
    __syncthreads();
    for (int j = tid; j < n; j += 256) sortedg[s0 + j] = sorted[j];
    if (tid < 128) {
        int node = b * 128 + tid;
        if (node < N) {
            nodestart[node] = s0 + soff[tid];
            nodedeg[node] = lcnt[tid];
        }
    }
}

// ---- fused GEMM + FiLM, B-stationary: m_t = relu(gamma*msg + beta) ----
__global__ __launch_bounds__(256, 2) void k_gemm_film(const unsigned short* __restrict__ featb,
                                                      const unsigned short* __restrict__ wcat,
                                                      unsigned short* __restrict__ m, int N,
                                                      int NT) {
    __shared__ unsigned char smem[2 * 16384];  // double-buffered 64x128 bf16, XOR-swizzled
    const int t = blockIdx.y;
    const int tid = threadIdx.x;
    const int w = tid >> 6, lane = tid & 63;
    const int lr = lane & 15, kg = lane >> 4;
    const int cbase = w * 32;

    const unsigned short* wt = wcat + (size_t)t * 384 * 128;
    bf16x8 B[4][3][2];
#pragma unroll
    for (int kkI = 0; kkI < 4; kkI++)
#pragma unroll
        for (int mat = 0; mat < 3; mat++)
#pragma unroll
            for (int cj = 0; cj < 2; cj++) {
                int col = mat * 128 + cbase + cj * 16 + lr;
                B[kkI][mat][cj] = *(const bf16x8*)(wt + (size_t)col * 128 + kkI * 32 + kg * 8);
            }

    auto stage = [&](int buf, int r0) {
#pragma unroll
        for (int it = 0; it < 4; it++) {
            int row = it * 16 + w * 4 + (lane >> 4);
            int gr = r0 + row;
            if (gr >= N) gr = N - 1;
            int x = ((lane & 15) * 16) ^ ((row & 7) << 4);
            const unsigned char* g = (const unsigned char*)featb + (size_t)gr * 256 + x;
            gload_lds16(g, smem + buf * 16384 + it * 4096 + w * 1024);
        }
    };

    unsigned short* mt = m + (size_t)t * N * DD;
    int buf = 0;
    int tile = blockIdx.x;
    if (tile < NT) stage(0, tile * 64);

    for (; tile < NT; tile += gridDim.x) {
        __syncthreads();
        int nxt = tile + gridDim.x;
        if (nxt < NT) stage(buf ^ 1, nxt * 64);

        const unsigned char* sm = smem + buf * 16384;
        f32x4 acc[4][3][2] = {};
#pragma unroll
        for (int kkI = 0; kkI < 4; kkI++) {
            bf16x8 a[4];
#pragma unroll
            for (int mi = 0; mi < 4; mi++) {
                int row = mi * 16 + lr;
                int kb = kkI * 64 + kg * 16;
                a[mi] = *(const bf16x8*)(sm + row * 256 + (kb ^ ((row & 7) << 4)));
            }
#pragma unroll
            for (int mi = 0; mi < 4; mi++)
#pragma unroll
                for (int mat = 0; mat < 3; mat++)
#pragma unroll
                    for (int cj = 0; cj < 2; cj++)
                        acc[mi][mat][cj] = __builtin_amdgcn_mfma_f32_16x16x32_bf16(
                            a[mi], B[kkI][mat][cj], acc[mi][mat][cj], 0, 0, 0);
        }

        const int r0 = tile * 64;
#pragma unroll
        for (int mi = 0; mi < 4; mi++)
#pragma unroll
            for (int cj = 0; cj < 2; cj++)
#pragma unroll
                for (int r = 0; r < 4; r++) {
                    int row = r0 + mi * 16 + kg * 4 + r;
                    if (row < N) {
                        float v = acc[mi][1][cj][r] * acc[mi][0][cj][r] + acc[mi][2][cj][r];
                        v = fmaxf(v, 0.0f);
                        __hip_bfloat16 bb = __float2bfloat16(v);
                        mt[(size_t)row * DD + cbase + cj * 16 + lr] =
                            *reinterpret_cast<unsigned short*>(&bb);
                    }
                }
        buf ^= 1;
    }
}

// ---- CSR gather + fused LayerNorm (at combined L3+HBM delivery roofline) ----
__global__ __launch_bounds__(256) void k_agg_ln(const unsigned int* __restrict__ sortedg,
                                                const int* __restrict__ nodestart,
                                                const int* __restrict__ nodedeg,
                                                const char* __restrict__ mbase,
                                                const float* __restrict__ lnw,
                                                const float* __restrict__ lnb,
                                                float* __restrict__ out, int N) {
    const int wv = threadIdx.x >> 6, lane = threadIdx.x & 63;
    const int node = blockIdx.x * 4 + wv;
    if (node >= N) return;
    const int start = nodestart[node], deg = nodedeg[node];
    const int q = lane >> 4, sl = lane & 15;
    const unsigned soff = (unsigned)sl * 16u;

    float a[8] = {0.f, 0.f, 0.f, 0.f, 0.f, 0.f, 0.f, 0.f};

    int e = 0;
    for (; e + 16 <= deg; e += 16) {
        unsigned r0 = sortedg[start + e + q];
        unsigned r1 = sortedg[start + e + 4 + q];
        unsigned r2 = sortedg[start + e + 8 + q];
        unsigned r3 = sortedg[start + e + 12 + q];
        uint4 p0 = *(const uint4*)(mbase + (r0 * 256u + soff));
        uint4 p1 = *(const uint4*)(mbase + (r1 * 256u + soff));
        uint4 p2 = *(const uint4*)(mbase + (r2 * 256u + soff));
        uint4 p3 = *(const uint4*)(mbase + (r3 * 256u + soff));
        a[0] += bflo(p0.x) + bflo(p1.x) + bflo(p2.x) + bflo(p3.x);
        a[1] += bfhi(p0.x) + bfhi(p1.x) + bfhi(p2.x) + bfhi(p3.x);
        a[2] += bflo(p0.y) + bflo(p1.y) + bflo(p2.y) + bflo(p3.y);
        a[3] += bfhi(p0.y) + bfhi(p1.y) + bfhi(p2.y) + bfhi(p3.y);
        a[4] += bflo(p0.z) + bflo(p1.z) + bflo(p2.z) + bflo(p3.z);
        a[5] += bfhi(p0.z) + bfhi(p1.z) + bfhi(p2.z) + bfhi(p3.z);
        a[6] += bflo(p0.w) + bflo(p1.w) + bflo(p2.w) + bflo(p3.w);
        a[7] += bfhi(p0.w) + bfhi(p1.w) + bfhi(p2.w) + bfhi(p3.w);
    }
    for (; e + 4 <= deg; e += 4) {
        unsigned r0 = sortedg[start + e + q];
        uint4 p0 = *(const uint4*)(mbase + (r0 * 256u + soff));
        a[0] += bflo(p0.x);
        a[1] += bfhi(p0.x);
        a[2] += bflo(p0.y);
        a[3] += bfhi(p0.y);
        a[4] += bflo(p0.z);
        a[5] += bfhi(p0.z);
        a[6] += bflo(p0.w);
        a[7] += bfhi(p0.w);
    }
    if (e < deg) {
        int idx = e + q;
        float w = (idx < deg) ? 1.0f : 0.0f;
        if (idx >= deg) idx = deg - 1;  // clamp to a valid edge (weight 0)
        unsigned r0 = sortedg[start + idx];
        uint4 p0 = *(const uint4*)(mbase + (r0 * 256u + soff));
        a[0] += w * bflo(p0.x);
        a[1] += w * bfhi(p0.x);
        a[2] += w * bflo(p0.y);
        a[3] += w * bfhi(p0.y);
        a[4] += w * bflo(p0.z);
        a[5] += w * bfhi(p0.z);
        a[6] += w * bflo(p0.w);
        a[7] += w * bfhi(p0.w);
    }

#pragma unroll
    for (int j = 0; j < 8; j++) {
        a[j] += __shfl_xor(a[j], 16, 64);
        a[j] += __shfl_xor(a[j], 32, 64);
    }
    float s = 0.f, ss = 0.f;
#pragma unroll
    for (int j = 0; j < 8; j++) {
        s += a[j];
        ss += a[j] * a[j];
    }
#pragma unroll
    for (int o = 1; o < 16; o <<= 1) {
        s += __shfl_xor(s, o, 64);
        ss += __shfl_xor(ss, o, 64);
    }
    float mu = s * (1.0f / 128.0f);
    float var = ss * (1.0f / 128.0f) - mu * mu;
    float rstd = rsqrtf(var + LN_EPS);
    if (q == 0) {
        float4 w0 = ((const float4*)lnw)[sl * 2];
        float4 w1 = ((const float4*)lnw)[sl * 2 + 1];
        float4 b0 = ((const float4*)lnb)[sl * 2];
        float4 b1 = ((const float4*)lnb)[sl * 2 + 1];
        float4 o0, o1;
        o0.x = (a[0] - mu) * rstd * w0.x + b0.x;
        o0.y = (a[1] - mu) * rstd * w0.y + b0.y;
        o0.z = (a[2] - mu) * rstd * w0.z + b0.z;
        o0.w = (a[3] - mu) * rstd * w0.w + b0.w;
        o1.x = (a[4] - mu) * rstd * w1.x + b1.x;
        o1.y = (a[5] - mu) * rstd * w1.y + b1.y;
        o1.z = (a[6] - mu) * rstd * w1.z + b1.z;
        o1.w = (a[7] - mu) * rstd * w1.w + b1.w;
        ((float4*)(out + (size_t)node * DD))[sl * 2] = o0;
        ((float4*)(out + (size_t)node * DD))[sl * 2 + 1] = o1;
    }
}

extern "C" void kernel_launch(void* const* d_in, const int* in_sizes, int n_in,
                              void* d_out, int out_size, void* d_ws, size_t ws_size,
                              hipStream_t stream) {
    const float* feat = (const float*)d_in[0];
    const float* W    = (const float*)d_in[1];
    const float* Wf   = (const float*)d_in[2];
    const float* lnw  = (const float*)d_in[3];
    const float* lnb  = (const float*)d_in[4];
    const int* src    = (const int*)d_in[5];
    const int* dst    = (const int*)d_in[6];
    float* out = (float*)d_out;

    const int N = in_sizes[0] / DD;   // 100000
    const int E = in_sizes[5] / 4;    // 400000
    const int E4 = 4 * E;
    const int NB = (N + 127) >> 7;    // 782 bins
    const int NBLK = (E4 + CHUNK - 1) / CHUNK;  // 391
    const int NT = (N + 63) / 64;     // 1563 row tiles
    const int n8 = N * DD / 8;

    size_t off = 0;
    char* ws = (char*)d_ws;
    auto alloc = [&](size_t bytes) -> void* {
        void* p = ws + off;
        off += (bytes + 255) & ~(size_t)255;
        return p;
    };
    unsigned short* m     = (unsigned short*)alloc((size_t)4 * N * DD * 2);  // 102.4 MB
    unsigned short* featb = (unsigned short*)alloc((size_t)N * DD * 2);      // 25.6 MB
    unsigned short* wcat  = (unsigned short*)alloc((size_t)4 * 384 * 128 * 2);
    int* H      = (int*)alloc((size_t)NB * NBLK * 4);                        // 1.2 MB
    int* C      = (int*)alloc((size_t)NB * 4);
    int* binoff = (int*)alloc((size_t)(NB + 1) * 4);
    unsigned int* rec     = (unsigned int*)alloc((size_t)E4 * 4);            // 6.4 MB
    unsigned int* sortedg = (unsigned int*)alloc((size_t)E4 * 4);            // 6.4 MB
    int* nodestart = (int*)alloc((size_t)N * 4);
    int* nodedeg   = (int*)alloc((size_t)N * 4);
    if (off > ws_size) return;

    k_head<<<2 * NBLK, 256, 0, stream>>>(feat, W, Wf, dst, featb, wcat, H,
                                         E4, NBLK, NB, n8);
    k_scanbin<<<(NB * 64 + 255) / 256, 256, 0, stream>>>(H, C, NBLK, NB);
    k_scan<<<1, 1024, 0, stream>>>(C, binoff, NB);
    k_place2<<<NBLK, 256, 0, stream>>>(src, dst, H, binoff, rec, N, E, E4, NBLK, NB);
    k_sortout<<<NB, 256, 0, stream>>>(rec, binoff, sortedg, nodestart, nodedeg, N);
    dim3 gg(128, 4);
    k_gemm_film<<<gg, 256, 0, stream>>>(featb, wcat, m, N, NT);
    k_agg_ln<<<(N + 3) / 4, 256, 0, stream>>>(sortedg, nodestart, nodedeg,
                                              (const char*)m, lnw, lnb, out, N);
}

// Round 11
// 169.531 us; speedup vs baseline: 2.1897x; 1.0497x over previous
//
#include <hip/hip_runtime.h>
#include <hip/hip_bf16.h>

#define DD 128
#define LN_EPS 1e-5f
#define BCAP 3072      // per-bin record cap (avg 2048, +22 sigma)
#define MAXBIN 1024    // LDS histogram capacity (NBIN = 782 for N=100000)
#define CHUNK 4096     // edges per binning block
#define EIDX_CAP 1024  // per-block staged edge-index cap (avg 64)

typedef __bf16 bf16x8 __attribute__((ext_vector_type(8)));
typedef float f32x4 __attribute__((ext_vector_type(4)));

__device__ __forceinline__ float bflo(unsigned int u) { return __uint_as_float(u << 16); }
__device__ __forceinline__ float bfhi(unsigned int u) { return __uint_as_float(u & 0xffff0000u); }

__device__ __forceinline__ void gload_lds16(const void* g, void* lds) {
    __builtin_amdgcn_global_load_lds(
        (const __attribute__((address_space(1))) unsigned int*)g,
        (__attribute__((address_space(3))) unsigned int*)lds, 16, 0, 0);
}

// ---- fused head: per-chunk histogram (blocks < NBLK) + feat/weight bf16 packing ----
__global__ __launch_bounds__(256) void k_head(const float* __restrict__ feat,
                                              const float* __restrict__ W,
                                              const float* __restrict__ Wf,
                                              const int* __restrict__ dst,
                                              unsigned short* __restrict__ fb,
                                              unsigned short* __restrict__ wcat,
                                              int* __restrict__ H, int* __restrict__ ticket,
                                              int E4, int NBLK, int NBIN, int n8) {
    __shared__ int h[MAXBIN];
    const int b = blockIdx.x, tid = threadIdx.x;
    if (b == 0 && tid == 0) *ticket = 0;  // for scanbin's last-block election

    if (b < NBLK) {
        for (int j = tid; j < NBIN; j += 256) h[j] = 0;
        __syncthreads();
        int base = b * CHUNK;
        int end = base + CHUNK < E4 ? base + CHUNK : E4;
        for (int i = base + tid; i < end; i += 256) atomicAdd(&h[dst[i] >> 7], 1);
        __syncthreads();
        for (int j = tid; j < NBIN; j += 256) H[(size_t)j * NBLK + b] = h[j];
    }

    const int gtid = b * 256 + tid, gsz = gridDim.x * 256;

    for (int i = gtid; i < n8; i += gsz) {
        const float4* p = (const float4*)feat + (size_t)i * 2;
        float4 v0 = p[0], v1 = p[1];
        float vv[8] = {v0.x, v0.y, v0.z, v0.w, v1.x, v1.y, v1.z, v1.w};
        unsigned short u[8];
#pragma unroll
        for (int j = 0; j < 8; j++) {
            __hip_bfloat16 bb = __float2bfloat16(vv[j]);
            u[j] = *reinterpret_cast<unsigned short*>(&bb);
        }
        uint4 o;
        o.x = u[0] | ((unsigned)u[1] << 16);
        o.y = u[2] | ((unsigned)u[3] << 16);
        o.z = u[4] | ((unsigned)u[5] << 16);
        o.w = u[6] | ((unsigned)u[7] << 16);
        ((uint4*)fb)[i] = o;
    }

    for (int i = gtid; i < 4 * 384 * 128; i += gsz) {
        int t = i / (384 * 128);
        int r = i % (384 * 128);
        int c = r / 128, k = r % 128;
        float v = (c < 128) ? W[((size_t)t * 128 + k) * 128 + c]
                            : Wf[((size_t)t * 128 + k) * 256 + (c - 128)];
        __hip_bfloat16 bb = __float2bfloat16(v);
        wcat[i] = *reinterpret_cast<unsigned short*>(&bb);
    }
}

// ---- P2+P3: per-bin exclusive scan across blocks; last block scans bin totals ----
__global__ __launch_bounds__(256) void k_scanbin(int* __restrict__ H, int* __restrict__ C,
                                                 int* __restrict__ binoff,
                                                 int* __restrict__ ticket,
                                                 int NBLK, int NBIN) {
    __shared__ int s[256];
    __shared__ int is_last;
    const int wv = (blockIdx.x * 256 + threadIdx.x) >> 6;
    const int lane = threadIdx.x & 63;
    const int tid = threadIdx.x;

    if (wv < NBIN) {
        int* row = H + (size_t)wv * NBLK;
        int run = 0;
        for (int base = 0; base < NBLK; base += 64) {
            int idx = base + lane;
            int v = (idx < NBLK) ? row[idx] : 0;
            int sc = v;
#pragma unroll
            for (int o = 1; o < 64; o <<= 1) {
                int u = __shfl_up(sc, o, 64);
                if (lane >= o) sc += u;
            }
            if (idx < NBLK) row[idx] = run + sc - v;  // exclusive
            run += __shfl(sc, 63, 64);
        }
        if (lane == 0) C[wv] = run;
    }

    __syncthreads();
    if (tid == 0) {
        __threadfence();
        int v = atomicAdd(ticket, 1);
        is_last = (v == (int)gridDim.x - 1);
    }
    __syncthreads();
    if (!is_last) return;
    __threadfence();  // acquire all C[]

    // scan of C[0..NBIN) -> binoff (4 bins/thread; verified in R9 phase C)
    int v[4];
    int tot = 0;
#pragma unroll
    for (int j = 0; j < 4; j++) {
        int idx = tid * 4 + j;
        v[j] = (idx < NBIN) ? C[idx] : 0;
        tot += v[j];
    }
    s[tid] = tot;
    __syncthreads();
    for (int st = 1; st < 256; st <<= 1) {
        int t = s[tid];
        int add = (tid >= st) ? s[tid - st] : 0;
        __syncthreads();
        s[tid] = t + add;
        __syncthreads();
    }
    int run = s[tid] - tot;  // exclusive
#pragma unroll
    for (int j = 0; j < 4; j++) {
        int idx = tid * 4 + j;
        if (idx < NBIN) binoff[idx] = run;
        run += v[j];
    }
    if (tid == 255) binoff[NBIN] = s[255];
}

// ---- P4: place records at deterministic offsets; LDS atomics only ----
__global__ __launch_bounds__(256) void k_place2(const int* __restrict__ src,
                                                const int* __restrict__ dst,
                                                const int* __restrict__ H,
                                                const int* __restrict__ binoff,
                                                unsigned int* __restrict__ rec,
                                                int N, int E, int E4, int NBLK, int NBIN) {
    __shared__ int fill[MAXBIN];
    const int b = blockIdx.x;
    for (int j = threadIdx.x; j < NBIN; j += 256)
        fill[j] = binoff[j] + H[(size_t)j * NBLK + b];
    __syncthreads();
    int base = b * CHUNK;
    int end = base + CHUNK < E4 ? base + CHUNK : E4;
    for (int i = base + threadIdx.x; i < end; i += 256) {
        int d = dst[i];
        int t = i / E;
        unsigned int r = ((unsigned)(d & 127) << 19) | (unsigned)(t * N + src[i]);
        int pos = atomicAdd(&fill[d >> 7], 1);
        rec[pos] = r;
    }
}

// ---- P5: per-bin LDS counting sort -> global CSR (sorted edges + packed meta) ----
__global__ __launch_bounds__(256) void k_sortout(const unsigned int* __restrict__ rec,
                                                 const int* __restrict__ binoff,
                                                 unsigned int* __restrict__ sortedg,
                                                 int2* __restrict__ nodemeta, int N) {
    __shared__ int lcnt[128], soff[128], sfill[128], tmp[128];
    __shared__ unsigned int sorted[BCAP];
    const int b = blockIdx.x, tid = threadIdx.x;
    const int s0 = binoff[b];
    int n = binoff[b + 1] - s0;
    if (n > BCAP) n = BCAP;

    if (tid < 128) lcnt[tid] = 0;
    __syncthreads();
    for (int j = tid; j < n; j += 256) atomicAdd(&lcnt[rec[s0 + j] >> 19], 1);
    __syncthreads();
    if (tid < 128) tmp[tid] = lcnt[tid];
    __syncthreads();
    for (int st = 1; st < 128; st <<= 1) {
        int t = 0, a = 0;
        if (tid < 128) {
            t = tmp[tid];
            a = (tid >= st) ? tmp[tid - st] : 0;
        }
        __syncthreads();
        if (tid < 128) tmp[tid] = t + a;
        __syncthreads();
    }
    if (tid < 128) {
        int ex = tmp[tid] - lcnt[tid];
        soff[tid] = ex;
        sfill[tid] = ex;
    }
    __syncthreads();
    for (int j = tid; j < n; j += 256) {
        unsigned int r = rec[s0 + j];
        int p = atomicAdd(&sfill[r >> 19], 1);
        sorted[p] = r & 0x7FFFFu;
    }
    __syncthreads();
    for (int j = tid; j < n; j += 256) sortedg[s0 + j] = sorted[j];
    if (tid < 128) {
        int node = b * 128 + tid;
        if (node < N) nodemeta[node] = make_int2(s0 + soff[tid], lcnt[tid]);
    }
}

// ---- fused GEMM + FiLM, B-stationary: m_t = relu(gamma*msg + beta) ----
__global__ __launch_bounds__(256, 2) void k_gemm_film(const unsigned short* __restrict__ featb,
                                                      const unsigned short* __restrict__ wcat,
                                                      unsigned short* __restrict__ m, int N,
                                                      int NT) {
    __shared__ unsigned char smem[2 * 16384];  // double-buffered 64x128 bf16, XOR-swizzled
    const int t = blockIdx.y;
    const int tid = threadIdx.x;
    const int w = tid >> 6, lane = tid & 63;
    const int lr = lane & 15, kg = lane >> 4;
    const int cbase = w * 32;

    const unsigned short* wt = wcat + (size_t)t * 384 * 128;
    bf16x8 B[4][3][2];
#pragma unroll
    for (int kkI = 0; kkI < 4; kkI++)
#pragma unroll
        for (int mat = 0; mat < 3; mat++)
#pragma unroll
            for (int cj = 0; cj < 2; cj++) {
                int col = mat * 128 + cbase + cj * 16 + lr;
                B[kkI][mat][cj] = *(const bf16x8*)(wt + (size_t)col * 128 + kkI * 32 + kg * 8);
            }

    auto stage = [&](int buf, int r0) {
#pragma unroll
        for (int it = 0; it < 4; it++) {
            int row = it * 16 + w * 4 + (lane >> 4);
            int gr = r0 + row;
            if (gr >= N) gr = N - 1;
            int x = ((lane & 15) * 16) ^ ((row & 7) << 4);
            const unsigned char* g = (const unsigned char*)featb + (size_t)gr * 256 + x;
            gload_lds16(g, smem + buf * 16384 + it * 4096 + w * 1024);
        }
    };

    unsigned short* mt = m + (size_t)t * N * DD;
    int buf = 0;
    int tile = blockIdx.x;
    if (tile < NT) stage(0, tile * 64);

    for (; tile < NT; tile += gridDim.x) {
        __syncthreads();
        int nxt = tile + gridDim.x;
        if (nxt < NT) stage(buf ^ 1, nxt * 64);

        const unsigned char* sm = smem + buf * 16384;
        f32x4 acc[4][3][2] = {};
#pragma unroll
        for (int kkI = 0; kkI < 4; kkI++) {
            bf16x8 a[4];
#pragma unroll
            for (int mi = 0; mi < 4; mi++) {
                int row = mi * 16 + lr;
                int kb = kkI * 64 + kg * 16;
                a[mi] = *(const bf16x8*)(sm + row * 256 + (kb ^ ((row & 7) << 4)));
            }
#pragma unroll
            for (int mi = 0; mi < 4; mi++)
#pragma unroll
                for (int mat = 0; mat < 3; mat++)
#pragma unroll
                    for (int cj = 0; cj < 2; cj++)
                        acc[mi][mat][cj] = __builtin_amdgcn_mfma_f32_16x16x32_bf16(
                            a[mi], B[kkI][mat][cj], acc[mi][mat][cj], 0, 0, 0);
        }

        const int r0 = tile * 64;
#pragma unroll
        for (int mi = 0; mi < 4; mi++)
#pragma unroll
            for (int cj = 0; cj < 2; cj++)
#pragma unroll
                for (int r = 0; r < 4; r++) {
                    int row = r0 + mi * 16 + kg * 4 + r;
                    if (row < N) {
                        float v = acc[mi][1][cj][r] * acc[mi][0][cj][r] + acc[mi][2][cj][r];
                        v = fmaxf(v, 0.0f);
                        __hip_bfloat16 bb = __float2bfloat16(v);
                        mt[(size_t)row * DD + cbase + cj * 16 + lr] =
                            *reinterpret_cast<unsigned short*>(&bb);
                    }
                }
        buf ^= 1;
    }
}

// ---- CSR gather + fused LayerNorm. Block = 4 consecutive nodes (contiguous CSR
// range): edge indices cooperatively staged in LDS -> no dependent global idx loads.
__global__ __launch_bounds__(256) void k_agg_ln(const unsigned int* __restrict__ sortedg,
                                                const int2* __restrict__ nodemeta,
                                                const char* __restrict__ mbase,
                                                const float* __restrict__ lnw,
                                                const float* __restrict__ lnb,
                                                float* __restrict__ out, int N) {
    __shared__ unsigned eidx[EIDX_CAP];
    __shared__ int smeta[8];
    const int wv = threadIdx.x >> 6, lane = threadIdx.x & 63;
    const int tid = threadIdx.x;
    const int node = blockIdx.x * 4 + wv;
    const int nclamp = node < N ? node : N - 1;
    const int2 meta = nodemeta[nclamp];
    if (lane == 0) {
        smeta[wv * 2] = meta.x;
        smeta[wv * 2 + 1] = meta.y;
    }
    __syncthreads();
    const int estart0 = smeta[0];
    const int total = smeta[6] + smeta[7] - estart0;
    const bool fits = (total <= EIDX_CAP);
    if (fits)
        for (int j = tid; j < total; j += 256) eidx[j] = sortedg[estart0 + j];
    __syncthreads();
    if (node >= N) return;

    const int deg = meta.y;
    const int q = lane >> 4, sl = lane & 15;
    const unsigned soff = (unsigned)sl * 16u;
    float a[8] = {0.f, 0.f, 0.f, 0.f, 0.f, 0.f, 0.f, 0.f};

    if (fits) {
        const int loff = meta.x - estart0;
        int e = 0;
        for (; e + 16 <= deg; e += 16) {
            unsigned r0 = eidx[loff + e + q];
            unsigned r1 = eidx[loff + e + 4 + q];
            unsigned r2 = eidx[loff + e + 8 + q];
            unsigned r3 = eidx[loff + e + 12 + q];
            uint4 p0 = *(const uint4*)(mbase + (r0 * 256u + soff));
            uint4 p1 = *(const uint4*)(mbase + (r1 * 256u + soff));
            uint4 p2 = *(const uint4*)(mbase + (r2 * 256u + soff));
            uint4 p3 = *(const uint4*)(mbase + (r3 * 256u + soff));
            a[0] += bflo(p0.x) + bflo(p1.x) + bflo(p2.x) + bflo(p3.x);
            a[1] += bfhi(p0.x) + bfhi(p1.x) + bfhi(p2.x) + bfhi(p3.x);
            a[2] += bflo(p0.y) + bflo(p1.y) + bflo(p2.y) + bflo(p3.y);
            a[3] += bfhi(p0.y) + bfhi(p1.y) + bfhi(p2.y) + bfhi(p3.y);
            a[4] += bflo(p0.z) + bflo(p1.z) + bflo(p2.z) + bflo(p3.z);
            a[5] += bfhi(p0.z) + bfhi(p1.z) + bfhi(p2.z) + bfhi(p3.z);
            a[6] += bflo(p0.w) + bflo(p1.w) + bflo(p2.w) + bflo(p3.w);
            a[7] += bfhi(p0.w) + bfhi(p1.w) + bfhi(p2.w) + bfhi(p3.w);
        }
        for (; e + 4 <= deg; e += 4) {
            unsigned r0 = eidx[loff + e + q];
            uint4 p0 = *(const uint4*)(mbase + (r0 * 256u + soff));
            a[0] += bflo(p0.x);
            a[1] += bfhi(p0.x);
            a[2] += bflo(p0.y);
            a[3] += bfhi(p0.y);
            a[4] += bflo(p0.z);
            a[5] += bfhi(p0.z);
            a[6] += bflo(p0.w);
            a[7] += bfhi(p0.w);
        }
        if (e < deg) {
            int idx = e + q;
            float w = (idx < deg) ? 1.0f : 0.0f;
            if (idx >= deg) idx = deg - 1;
            unsigned r0 = eidx[loff + idx];
            uint4 p0 = *(const uint4*)(mbase + (r0 * 256u + soff));
            a[0] += w * bflo(p0.x);
            a[1] += w * bfhi(p0.x);
            a[2] += w * bflo(p0.y);
            a[3] += w * bfhi(p0.y);
            a[4] += w * bflo(p0.z);
            a[5] += w * bfhi(p0.z);
            a[6] += w * bflo(p0.w);
            a[7] += w * bfhi(p0.w);
        }
    } else {  // rare fallback: direct global index loads
        const int start = meta.x;
        int e = 0;
        for (; e + 4 <= deg; e += 4) {
            unsigned r0 = sortedg[start + e + q];
            uint4 p0 = *(const uint4*)(mbase + (r0 * 256u + soff));
            a[0] += bflo(p0.x);
            a[1] += bfhi(p0.x);
            a[2] += bflo(p0.y);
            a[3] += bfhi(p0.y);
            a[4] += bflo(p0.z);
            a[5] += bfhi(p0.z);
            a[6] += bflo(p0.w);
            a[7] += bfhi(p0.w);
        }
        if (e < deg) {
            int idx = e + q;
            float w = (idx < deg) ? 1.0f : 0.0f;
            if (idx >= deg) idx = deg - 1;
            unsigned r0 = sortedg[start + idx];
            uint4 p0 = *(const uint4*)(mbase + (r0 * 256u + soff));
            a[0] += w * bflo(p0.x);
            a[1] += w * bfhi(p0.x);
            a[2] += w * bflo(p0.y);
            a[3] += w * bfhi(p0.y);
            a[4] += w * bflo(p0.z);
            a[5] += w * bfhi(p0.z);
            a[6] += w * bflo(p0.w);
            a[7] += w * bfhi(p0.w);
        }
    }

#pragma unroll
    for (int j = 0; j < 8; j++) {
        a[j] += __shfl_xor(a[j], 16, 64);
        a[j] += __shfl_xor(a[j], 32, 64);
    }
    float s = 0.f, ss = 0.f;
#pragma unroll
    for (int j = 0; j < 8; j++) {
        s += a[j];
        ss += a[j] * a[j];
    }
#pragma unroll
    for (int o = 1; o < 16; o <<= 1) {
        s += __shfl_xor(s, o, 64);
        ss += __shfl_xor(ss, o, 64);
    }
    float mu = s * (1.0f / 128.0f);
    float var = ss * (1.0f / 128.0f) - mu * mu;
    float rstd = rsqrtf(var + LN_EPS);
    if (q == 0) {
        float4 w0 = ((const float4*)lnw)[sl * 2];
        float4 w1 = ((const float4*)lnw)[sl * 2 + 1];
        float4 b0 = ((const float4*)lnb)[sl * 2];
        float4 b1 = ((const float4*)lnb)[sl * 2 + 1];
        float4 o0, o1;
        o0.x = (a[0] - mu) * rstd * w0.x + b0.x;
        o0.y = (a[1] - mu) * rstd * w0.y + b0.y;
        o0.z = (a[2] - mu) * rstd * w0.z + b0.z;
        o0.w = (a[3] - mu) * rstd * w0.w + b0.w;
        o1.x = (a[4] - mu) * rstd * w1.x + b1.x;
        o1.y = (a[5] - mu) * rstd * w1.y + b1.y;
        o1.z = (a[6] - mu) * rstd * w1.z + b1.z;
        o1.w = (a[7] - mu) * rstd * w1.w + b1.w;
        ((float4*)(out + (size_t)node * DD))[sl * 2] = o0;
        ((float4*)(out + (size_t)node * DD))[sl * 2 + 1] = o1;
    }
}

extern "C" void kernel_launch(void* const* d_in, const int* in_sizes, int n_in,
                              void* d_out, int out_size, void* d_ws, size_t ws_size,
                              hipStream_t stream) {
    const float* feat = (const float*)d_in[0];
    const float* W    = (const float*)d_in[1];
    const float* Wf   = (const float*)d_in[2];
    const float* lnw  = (const float*)d_in[3];
    const float* lnb  = (const float*)d_in[4];
    const int* src    = (const int*)d_in[5];
    const int* dst    = (const int*)d_in[6];
    float* out = (float*)d_out;

    const int N = in_sizes[0] / DD;   // 100000
    const int E = in_sizes[5] / 4;    // 400000
    const int E4 = 4 * E;
    const int NB = (N + 127) >> 7;    // 782 bins
    const int NBLK = (E4 + CHUNK - 1) / CHUNK;  // 391
    const int NT = (N + 63) / 64;     // 1563 row tiles
    const int n8 = N * DD / 8;

    size_t off = 0;
    char* ws = (char*)d_ws;
    auto alloc = [&](size_t bytes) -> void* {
        void* p = ws + off;
        off += (bytes + 255) & ~(size_t)255;
        return p;
    };
    unsigned short* m     = (unsigned short*)alloc((size_t)4 * N * DD * 2);  // 102.4 MB
    unsigned short* featb = (unsigned short*)alloc((size_t)N * DD * 2);      // 25.6 MB
    unsigned short* wcat  = (unsigned short*)alloc((size_t)4 * 384 * 128 * 2);
    int* H      = (int*)alloc((size_t)NB * NBLK * 4);                        // 1.2 MB
    int* C      = (int*)alloc((size_t)NB * 4);
    int* binoff = (int*)alloc((size_t)(NB + 1) * 4);
    int* ticket = (int*)alloc(256);
    unsigned int* rec     = (unsigned int*)alloc((size_t)E4 * 4);            // 6.4 MB
    unsigned int* sortedg = (unsigned int*)alloc((size_t)E4 * 4);            // 6.4 MB
    int2* nodemeta = (int2*)alloc((size_t)N * 8);
    if (off > ws_size) return;

    k_head<<<2 * NBLK, 256, 0, stream>>>(feat, W, Wf, dst, featb, wcat, H, ticket,
                                         E4, NBLK, NB, n8);
    k_scanbin<<<(NB * 64 + 255) / 256, 256, 0, stream>>>(H, C, binoff, ticket, NBLK, NB);
    k_place2<<<NBLK, 256, 0, stream>>>(src, dst, H, binoff, rec, N, E, E4, NBLK, NB);
    k_sortout<<<NB, 256, 0, stream>>>(rec, binoff, sortedg, nodemeta, N);
    dim3 gg(128, 4);
    k_gemm_film<<<gg, 256, 0, stream>>>(featb, wcat, m, N, NT);
    k_agg_ln<<<(N + 3) / 4, 256, 0, stream>>>(sortedg, nodemeta,
                                              (const char*)m, lnw, lnb, out, N);
}